// Round 8
// baseline (17.809 us; speedup 1.0000x reference)
//
#include <hip/hip_runtime.h>

// Problem constants (from reference)
constexpr int   B  = 32, N = 17;            // batch, keypoints
constexpr int   BN = B * N;                 // 544
constexpr int   H = 128, W = 128, HW = H * W;
constexpr int   CHUNKS_PER_BN = 4;          // 4096 px per chunk
constexpr int   NCHUNK = BN * CHUNKS_PER_BN;// 2176 chunks
constexpr int   GRID1  = 2048;              // 256 CU x 8 blocks: one resident round
constexpr float L_IMG   = 512.0f;
constexpr float STRIDE  = 4.0f;             // L // W
constexpr float START   = STRIDE / 2.0f - 0.5f;     // 1.5
constexpr float INV2SG2 = 1.0f / (2.0f * 8.0f * 8.0f);
constexpr float TRUNCV  = 4.6052f;

// Kernel 1: 2048 blocks grid-stride over 2176 chunks (4 chunks per bn).
// Masked-out keypoints never affect the output -> skip their reads.
__global__ __launch_bounds__(256)
void heatmap_loss_per_kp(const float* __restrict__ pred,   // [BN, HW]
                         const float* __restrict__ labels, // [BN, 2]
                         const float* __restrict__ mask,   // [BN]
                         float* __restrict__ part)         // [NCHUNK]
{
    const int t    = threadIdx.x;
    const int wave = t >> 6;
    __shared__ float sacc[4];

    for (int c = blockIdx.x; c < NCHUNK; c += GRID1) {
        const int bn = c >> 2;
        const int q  = c & 3;

        float a = 0.0f;
        if (mask[bn] > 0.0f) {   // block-uniform; masked kp's 16 KB never read
            const float lx = labels[bn * 2 + 0];
            const float ly = labels[bn * 2 + 1];
            const float cx = fminf(fmaxf((lx * 0.5f + 0.5f) * L_IMG, 0.0f), L_IMG - 1.0f);
            const float cy = fminf(fmaxf((ly * 0.5f + 0.5f) * L_IMG, 0.0f), L_IMG - 1.0f);

            const float4* p4 = reinterpret_cast<const float4*>(pred + (size_t)bn * HW) + q * 1024;

            #pragma unroll
            for (int j = 0; j < 4; ++j) {
                const int f4 = j * 256 + t;          // float4 index within quarter
                const float4 v = p4[f4];
                const int e = (q * 1024 + f4) * 4;   // element index within bn
                const int h = e >> 7;
                const int w = e & 127;
                const float dy  = fmaf(STRIDE, (float)h, START) - cy;
                const float dy2 = dy * dy;
                const float pv[4] = { v.x, v.y, v.z, v.w };
                #pragma unroll
                for (int k = 0; k < 4; ++k) {
                    const float dx   = fmaf(STRIDE, (float)(w + k), START) - cx;
                    const float d2   = fmaf(dx, dx, dy2);
                    const float expo = d2 * INV2SG2;
                    const float gt   = (expo > TRUNCV) ? 0.0f : __expf(-expo);
                    const float diff = pv[k] - gt;
                    a = fmaf(diff, diff, a);
                }
            }
            #pragma unroll
            for (int off = 32; off > 0; off >>= 1)
                a += __shfl_down(a, off, 64);
        }

        if ((t & 63) == 0) sacc[wave] = a;
        __syncthreads();
        if (t == 0)
            part[c] = (sacc[0] + sacc[1] + sacc[2] + sacc[3]) * (1.0f / (float)HW);
        __syncthreads();   // protect sacc before next chunk iteration
    }
}

// Kernel 2: one wave, no LDS, deterministic final reduction.
__global__ __launch_bounds__(64)
void heatmap_loss_final(const float* __restrict__ part,    // [NCHUNK]
                        const float* __restrict__ mask,    // [BN]
                        float* __restrict__ out)           // [1]
{
    const int t = threadIdx.x;
    float tot = 0.0f, nv = 0.0f;
    #pragma unroll
    for (int i = t; i < NCHUNK; i += 64) tot += part[i];
    #pragma unroll
    for (int i = t; i < BN;     i += 64) nv  += mask[i];
    #pragma unroll
    for (int off = 32; off > 0; off >>= 1) {
        tot += __shfl_down(tot, off, 64);
        nv  += __shfl_down(nv,  off, 64);
    }
    if (t == 0)
        out[0] = (nv > 0.0f) ? (tot / fmaxf(nv, 1.0f)) : 0.0f;
}

extern "C" void kernel_launch(void* const* d_in, const int* in_sizes, int n_in,
                              void* d_out, int out_size, void* d_ws, size_t ws_size,
                              hipStream_t stream) {
    const float* pred   = (const float*)d_in[0]; // [B,N,H,W]
    const float* labels = (const float*)d_in[1]; // [B,N,2]
    const float* mask   = (const float*)d_in[2]; // [B,N]
    float* out = (float*)d_out;
    float* ws  = (float*)d_ws;                   // NCHUNK * 4 B

    heatmap_loss_per_kp<<<GRID1, 256, 0, stream>>>(pred, labels, mask, ws);
    heatmap_loss_final<<<1, 64, 0, stream>>>(ws, mask, out);
}

// Round 9
// 13.142 us; speedup vs baseline: 1.3551x; 1.3551x over previous
//
#include <hip/hip_runtime.h>

// Problem constants (from reference)
constexpr int   B  = 32, N = 17;          // batch, keypoints
constexpr int   BN = B * N;               // 544
constexpr int   H = 128, W = 128, HW = H * W;
constexpr int   BLOCKS_PER_BN = 4;        // 4096 px per block
constexpr int   NPART = BN * BLOCKS_PER_BN; // 2176 partials
constexpr float L_IMG   = 512.0f;
constexpr float STRIDE  = 4.0f;           // L // W
constexpr float START   = STRIDE / 2.0f - 0.5f;   // 1.5
constexpr float INV2SG2 = 1.0f / (2.0f * 8.0f * 8.0f);
constexpr float TRUNCV  = 4.6052f;

// Kernel 1: 4 blocks per (b,n). Masked-out keypoints never touch the
// output (loss is multiplied by valid), so skip their reads entirely.
__global__ __launch_bounds__(256)
void heatmap_loss_per_kp(const float* __restrict__ pred,   // [BN, HW]
                         const float* __restrict__ labels, // [BN, 2]
                         const float* __restrict__ mask,   // [BN]
                         float* __restrict__ part)         // [NPART]
{
    const int bid = blockIdx.x;
    const int bn  = bid >> 2;
    const int q   = bid & 3;
    const int t   = threadIdx.x;

    // Block-uniform early exit for masked-out keypoints.
    if (mask[bn] <= 0.0f) {
        if (t == 0) part[bid] = 0.0f;   // fresh write every call (no stale ws state)
        return;
    }

    const float lx = labels[bn * 2 + 0];
    const float ly = labels[bn * 2 + 1];
    const float cx = fminf(fmaxf((lx * 0.5f + 0.5f) * L_IMG, 0.0f), L_IMG - 1.0f);
    const float cy = fminf(fmaxf((ly * 0.5f + 0.5f) * L_IMG, 0.0f), L_IMG - 1.0f);

    const float4* p4 = reinterpret_cast<const float4*>(pred + (size_t)bn * HW) + q * 1024;

    float acc = 0.0f;
    #pragma unroll
    for (int j = 0; j < 4; ++j) {
        const int f4 = j * 256 + t;           // float4 index within quarter [0,1024)
        const float4 v = p4[f4];
        const int e = (q * 1024 + f4) * 4;    // element index within bn
        const int h = e >> 7;                 // row
        const int w = e & 127;                // col of first element
        const float dy  = fmaf(STRIDE, (float)h, START) - cy;
        const float dy2 = dy * dy;

        const float pv[4] = { v.x, v.y, v.z, v.w };
        #pragma unroll
        for (int k = 0; k < 4; ++k) {
            const float dx   = fmaf(STRIDE, (float)(w + k), START) - cx;
            const float d2   = fmaf(dx, dx, dy2);
            const float expo = d2 * INV2SG2;
            const float gt   = (expo > TRUNCV) ? 0.0f : __expf(-expo);
            const float diff = pv[k] - gt;
            acc = fmaf(diff, diff, acc);
        }
    }

    // wave (64-lane) shuffle reduce
    #pragma unroll
    for (int off = 32; off > 0; off >>= 1)
        acc += __shfl_down(acc, off, 64);

    __shared__ float sacc[4];
    const int wave = t >> 6;
    if ((t & 63) == 0) sacc[wave] = acc;
    __syncthreads();

    if (t == 0)
        part[bid] = (sacc[0] + sacc[1] + sacc[2] + sacc[3]) * (1.0f / (float)HW);
}

// Kernel 2: single block, deterministic final reduction.
__global__ __launch_bounds__(256)
void heatmap_loss_final(const float* __restrict__ part,    // [NPART]
                        const float* __restrict__ mask,    // [BN]
                        float* __restrict__ out)           // [1]
{
    const int t = threadIdx.x;
    float tot = 0.0f, nv = 0.0f;
    #pragma unroll
    for (int i = t; i < NPART; i += 256) tot += part[i];
    for (int i = t; i < BN;    i += 256) nv  += mask[i];
    #pragma unroll
    for (int off = 32; off > 0; off >>= 1) {
        tot += __shfl_down(tot, off, 64);
        nv  += __shfl_down(nv,  off, 64);
    }
    __shared__ float st[4], sn[4];
    const int wave = t >> 6;
    if ((t & 63) == 0) { st[wave] = tot; sn[wave] = nv; }
    __syncthreads();
    if (t == 0) {
        const float T  = st[0] + st[1] + st[2] + st[3];
        const float NV = sn[0] + sn[1] + sn[2] + sn[3];
        out[0] = (NV > 0.0f) ? (T / fmaxf(NV, 1.0f)) : 0.0f;
    }
}

extern "C" void kernel_launch(void* const* d_in, const int* in_sizes, int n_in,
                              void* d_out, int out_size, void* d_ws, size_t ws_size,
                              hipStream_t stream) {
    const float* pred   = (const float*)d_in[0]; // [B,N,H,W]
    const float* labels = (const float*)d_in[1]; // [B,N,2]
    const float* mask   = (const float*)d_in[2]; // [B,N]
    float* out = (float*)d_out;
    float* ws  = (float*)d_ws;                   // needs NPART*4 = 8704 bytes

    heatmap_loss_per_kp<<<NPART, 256, 0, stream>>>(pred, labels, mask, ws);
    heatmap_loss_final<<<1, 256, 0, stream>>>(ws, mask, out);
}